// Round 9
// baseline (380.989 us; speedup 1.0000x reference)
//
#include <hip/hip_runtime.h>

// Wiener filter, x: [16,3,1024,1024] fp32, ksize=7 (hardcoded). Two kernels:
//   pass<0>: per-strip partial of sum(local_var) via identity
//            sum(var) = (1/49)*sum_w(x^2) - sum(m^2) -> d_ws[bc*16+strip]
//   pass<1>: recompute mean/var per pixel, Wiener combine, nontemporal store.
// Separable box: vertical sliding column sums in registers (8-deep register
// queue -> 1 global load per row), horizontal 7-tap via LDS rows of column
// sums with reflect halos. FOUR LDS buffer sets -> TWO rows per barrier
// (32 barriers/strip instead of 64); pair p's buffers are only rewritten at
// pair p+2, behind pair p+1's barrier, so no trailing barrier is needed.

#define HH 1024
#define WW 1024
#define RB 64            // rows per block strip
#define NT 256           // threads per block (each owns 4 contiguous columns)
#define NIMG 48          // B*C = 16*3
#define STRIPS (HH / RB) // 16

typedef float f32x4 __attribute__((ext_vector_type(4)));

__device__ __forceinline__ int vrefl(int i) {
    // jnp.pad mode='reflect': -1 -> 1, 1024 -> 1022
    i = (i < 0) ? -i : i;
    return (i >= HH) ? (2 * HH - 2 - i) : i;
}

__device__ __forceinline__ float wvf(int r) {
    // vertical box coverage weight under reflect padding
    if (r <= 3) return (r == 0) ? 4.0f : 8.0f;
    if (r >= HH - 4) return (r == HH - 1) ? 4.0f : 8.0f;
    return 7.0f;
}

__device__ __forceinline__ float4 ld4(const float* p) {
    return *reinterpret_cast<const float4*>(p);
}

template <int FINAL>
__global__ __launch_bounds__(NT, 3) void wiener_pass(const float* __restrict__ x,
                                                     float* __restrict__ nsum,
                                                     float* __restrict__ out) {
    // 4 buffer sets: [pairparity*2 + rowinpair][4-halo | 1024 | 4-halo]
    __shared__ __align__(16) float s_cs[4][WW + 8];
    __shared__ __align__(16) float s_c2[4][WW + 8]; // untouched when !FINAL
    __shared__ float s_red[NT / 64];

    const int t = threadIdx.x;
    const int r0 = blockIdx.x * RB;
    const int bc = blockIdx.y;
    const int c0 = t * 4;

    const float* img = x + (size_t)bc * (HH * WW);

    // horizontal coverage weights for this thread's 4 columns (pass0 only)
    float whx = 7.f, why = 7.f, whz = 7.f, whw = 7.f;
    if (t == 0) { whx = 4.f; why = 8.f; whz = 8.f; whw = 8.f; }
    if (t == NT - 1) { whx = 8.f; why = 8.f; whz = 8.f; whw = 4.f; }

    // --- register queue: slot k holds x row with (row & 7) == k ---
    float4 q0, q1, q2, q3, q4, q5, q6, q7;
    q5 = ld4(img + (size_t)vrefl(r0 - 3) * WW + c0);
    q6 = ld4(img + (size_t)vrefl(r0 - 2) * WW + c0);
    q7 = ld4(img + (size_t)vrefl(r0 - 1) * WW + c0);
    q0 = ld4(img + (size_t)(r0 + 0) * WW + c0);
    q1 = ld4(img + (size_t)(r0 + 1) * WW + c0);
    q2 = ld4(img + (size_t)(r0 + 2) * WW + c0);

    float csx = 0.f, csy = 0.f, csz = 0.f, csw = 0.f;
    float c2x = 0.f, c2y = 0.f, c2z = 0.f, c2w = 0.f; // FINAL only
    float sq_acc = 0.f, msq_acc = 0.f;
    const float inv = 1.0f / 49.0f;

#define ACCROW(Q)                                                         \
    csx += Q.x; csy += Q.y; csz += Q.z; csw += Q.w;                       \
    if (FINAL) {                                                          \
        c2x = fmaf(Q.x, Q.x, c2x); c2y = fmaf(Q.y, Q.y, c2y);             \
        c2z = fmaf(Q.z, Q.z, c2z); c2w = fmaf(Q.w, Q.w, c2w);             \
    }
    ACCROW(q5) ACCROW(q6) ACCROW(q7) ACCROW(q0) ACCROW(q1) ACCROW(q2)
#undef ACCROW
    if (!FINAL) { // rows r0..r0+2 are in-strip: weighted x^2, once each
#define SQROW(Q, R)                                                       \
        {                                                                 \
            float d = fmaf(Q.x * Q.x, whx, fmaf(Q.y * Q.y, why,           \
                      fmaf(Q.z * Q.z, whz, Q.w * Q.w * whw)));            \
            sq_acc = fmaf(d, wvf(R), sq_acc);                             \
        }
        SQROW(q0, r0) SQROW(q1, r0 + 1) SQROW(q2, r0 + 2)
#undef SQROW
    }

    float np = 0.f;
    if (FINAL) {
        float s = 0.f;
#pragma unroll
        for (int i = 0; i < STRIPS; ++i) s += nsum[bc * STRIPS + i];
        np = s * (1.0f / ((float)HH * (float)WW));
    }

    float* oimg = FINAL ? (out + (size_t)bc * (HH * WW)) : nullptr;

// publish current register state (csx.. / c2x..) as a column-sum row
#define PUBLISH(CS, C2)                                                        \
    reinterpret_cast<float4*>(CS)[t + 1] = make_float4(csx, csy, csz, csw);    \
    if (FINAL)                                                                 \
        reinterpret_cast<float4*>(C2)[t + 1] = make_float4(c2x, c2y, c2z, c2w);\
    if (t == 0) {                                                              \
        CS[0] = csx; CS[1] = csw; CS[2] = csz; CS[3] = csy;                    \
        if (FINAL) { C2[0] = c2x; C2[1] = c2w; C2[2] = c2z; C2[3] = c2y; }     \
    }                                                                          \
    if (t == NT - 1) {                                                         \
        CS[4 + WW] = csz; CS[4 + WW + 1] = csy;                                \
        CS[4 + WW + 2] = csx; CS[4 + WW + 3] = csw;                            \
        if (FINAL) {                                                           \
            C2[4 + WW] = c2z; C2[4 + WW + 1] = c2y;                            \
            C2[4 + WW + 2] = c2x; C2[4 + WW + 3] = c2w;                        \
        }                                                                      \
    }

// horizontal 7-tap + Wiener/reduce for one row; MID*/T2* are that row's
// register state (snapshot for row r, live regs for row r+1)
#define COMPUTE(CS, C2, MIDX, MIDY, MIDZ, MIDW, T2X, T2Y, T2Z, T2W, R, QX)     \
    {                                                                          \
        float4 la = reinterpret_cast<const float4*>(CS)[t];                    \
        float4 lc = reinterpret_cast<const float4*>(CS)[t + 2];                \
        float s0 = la.y + la.z + la.w + MIDX + MIDY + MIDZ + MIDW;             \
        float s1 = s0 - la.y + lc.x;                                           \
        float s2 = s1 - la.z + lc.y;                                           \
        float s3 = s2 - la.w + lc.z;                                           \
        float m0 = s0 * inv, m1 = s1 * inv, m2 = s2 * inv, m3 = s3 * inv;      \
        if (FINAL) {                                                           \
            float4 ma = reinterpret_cast<const float4*>(C2)[t];                \
            float4 mc = reinterpret_cast<const float4*>(C2)[t + 2];            \
            float u0 = ma.y + ma.z + ma.w + T2X + T2Y + T2Z + T2W;             \
            float u1 = u0 - ma.y + mc.x;                                       \
            float u2 = u1 - ma.z + mc.y;                                       \
            float u3 = u2 - ma.w + mc.z;                                       \
            float v0 = fmaf(u0, inv, -m0 * m0);                                \
            float v1 = fmaf(u1, inv, -m1 * m1);                                \
            float v2 = fmaf(u2, inv, -m2 * m2);                                \
            float v3 = fmaf(u3, inv, -m3 * m3);                                \
            float g0 = 1.0f - np / v0;                                         \
            float g1 = 1.0f - np / v1;                                         \
            float g2 = 1.0f - np / v2;                                         \
            float g3 = 1.0f - np / v3;                                         \
            float o0 = fmaf(QX.x - m0, g0, m0);                                \
            float o1 = fmaf(QX.y - m1, g1, m1);                                \
            float o2 = fmaf(QX.z - m2, g2, m2);                                \
            float o3 = fmaf(QX.w - m3, g3, m3);                                \
            o0 = (v0 < np) ? m0 : o0;                                          \
            o1 = (v1 < np) ? m1 : o1;                                          \
            o2 = (v2 < np) ? m2 : o2;                                          \
            o3 = (v3 < np) ? m3 : o3;                                          \
            f32x4 ov4 = {o0, o1, o2, o3};                                      \
            __builtin_nontemporal_store(ov4,                                   \
                reinterpret_cast<f32x4*>(oimg + (size_t)(R) * WW + c0));       \
        } else {                                                               \
            msq_acc = fmaf(m0, m0, msq_acc);                                   \
            msq_acc = fmaf(m1, m1, msq_acc);                                   \
            msq_acc = fmaf(m2, m2, msq_acc);                                   \
            msq_acc = fmaf(m3, m3, msq_acc);                                   \
        }                                                                      \
    }

// two rows (r=rbase+J, r+1), ONE barrier. QN0/QO0/QX0: slots (J+3)&7/(J+5)&7/J.
#define ROWPAIR(J, QN0, QO0, QX0, QN1, QO1, QX1, CSA, C2A, CSB, C2B)           \
    {                                                                          \
        const int r = rbase + (J);                                             \
        QN0 = ld4(img + (size_t)vrefl(r + 3) * WW + c0);                       \
        csx += QN0.x; csy += QN0.y; csz += QN0.z; csw += QN0.w;                \
        if (FINAL) {                                                           \
            c2x = fmaf(QN0.x, QN0.x, c2x); c2y = fmaf(QN0.y, QN0.y, c2y);      \
            c2z = fmaf(QN0.z, QN0.z, c2z); c2w = fmaf(QN0.w, QN0.w, c2w);      \
        } else if (r < r0 + RB - 3) {                                          \
            float d = fmaf(QN0.x * QN0.x, whx, fmaf(QN0.y * QN0.y, why,        \
                      fmaf(QN0.z * QN0.z, whz, QN0.w * QN0.w * whw)));         \
            sq_acc = fmaf(d, wvf(r + 3), sq_acc);                              \
        }                                                                      \
        PUBLISH(CSA, C2A)                                                      \
        const float ax = csx, ay = csy, az = csz, aw = csw; /* row r state */  \
        float a2x = 0.f, a2y = 0.f, a2z = 0.f, a2w = 0.f;                      \
        if (FINAL) { a2x = c2x; a2y = c2y; a2z = c2z; a2w = c2w; }             \
        csx -= QO0.x; csy -= QO0.y; csz -= QO0.z; csw -= QO0.w;                \
        if (FINAL) {                                                           \
            c2x = fmaf(-QO0.x, QO0.x, c2x); c2y = fmaf(-QO0.y, QO0.y, c2y);    \
            c2z = fmaf(-QO0.z, QO0.z, c2z); c2w = fmaf(-QO0.w, QO0.w, c2w);    \
        }                                                                      \
        QN1 = ld4(img + (size_t)vrefl(r + 4) * WW + c0);                       \
        csx += QN1.x; csy += QN1.y; csz += QN1.z; csw += QN1.w;                \
        if (FINAL) {                                                           \
            c2x = fmaf(QN1.x, QN1.x, c2x); c2y = fmaf(QN1.y, QN1.y, c2y);      \
            c2z = fmaf(QN1.z, QN1.z, c2z); c2w = fmaf(QN1.w, QN1.w, c2w);      \
        } else if (r + 1 < r0 + RB - 3) {                                      \
            float d = fmaf(QN1.x * QN1.x, whx, fmaf(QN1.y * QN1.y, why,        \
                      fmaf(QN1.z * QN1.z, whz, QN1.w * QN1.w * whw)));         \
            sq_acc = fmaf(d, wvf(r + 4), sq_acc);                              \
        }                                                                      \
        PUBLISH(CSB, C2B)                                                      \
        __syncthreads();                                                       \
        COMPUTE(CSA, C2A, ax, ay, az, aw, a2x, a2y, a2z, a2w, r, QX0)          \
        COMPUTE(CSB, C2B, csx, csy, csz, csw, c2x, c2y, c2z, c2w, r + 1, QX1)  \
        csx -= QO1.x; csy -= QO1.y; csz -= QO1.z; csw -= QO1.w;                \
        if (FINAL) {                                                           \
            c2x = fmaf(-QO1.x, QO1.x, c2x); c2y = fmaf(-QO1.y, QO1.y, c2y);    \
            c2z = fmaf(-QO1.z, QO1.z, c2z); c2w = fmaf(-QO1.w, QO1.w, c2w);    \
        }                                                                      \
    }

    for (int it = 0; it < RB / 8; ++it) {
        const int rbase = r0 + it * 8;
        ROWPAIR(0, q3, q5, q0, q4, q6, q1, s_cs[0], s_c2[0], s_cs[1], s_c2[1])
        ROWPAIR(2, q5, q7, q2, q6, q0, q3, s_cs[2], s_c2[2], s_cs[3], s_c2[3])
        ROWPAIR(4, q7, q1, q4, q0, q2, q5, s_cs[0], s_c2[0], s_cs[1], s_c2[1])
        ROWPAIR(6, q1, q3, q6, q2, q4, q7, s_cs[2], s_c2[2], s_cs[3], s_c2[3])
    }
#undef ROWPAIR
#undef COMPUTE
#undef PUBLISH

    if (!FINAL) {
        // block partial of sum(var): (1/49)*sum_w(x^2) - sum(m^2)
        float vacc = fmaf(sq_acc, inv, -msq_acc);
#pragma unroll
        for (int off = 32; off > 0; off >>= 1)
            vacc += __shfl_down(vacc, off, 64);
        if ((t & 63) == 0) s_red[t >> 6] = vacc;
        __syncthreads();
        if (t == 0) {
            float b = (s_red[0] + s_red[1]) + (s_red[2] + s_red[3]);
            nsum[bc * STRIPS + blockIdx.x] = b; // per-strip partial, no atomic
        }
    }
}

extern "C" void kernel_launch(void* const* d_in, const int* in_sizes, int n_in,
                              void* d_out, int out_size, void* d_ws, size_t ws_size,
                              hipStream_t stream) {
    const float* x = (const float*)d_in[0];
    float* out = (float*)d_out;
    float* nsum = (float*)d_ws; // 48*16 per-strip partials (every slot written)

    dim3 grid(STRIPS, NIMG); // 16 x 48 = 768 blocks, 3 per CU, 12 waves/CU
    wiener_pass<0><<<grid, NT, 0, stream>>>(x, nsum, nullptr);
    wiener_pass<1><<<grid, NT, 0, stream>>>(x, nsum, out);
}